// Round 3
// baseline (1550.224 us; speedup 1.0000x reference)
//
#include <hip/hip_runtime.h>
#include <math.h>

#define CB 8
#define CNX 512
#define CNR 512
#define CD 256
#define CH 256

__device__ __forceinline__ float fast_rcp(float x) {
#if __has_builtin(__builtin_amdgcn_rcpf)
  return __builtin_amdgcn_rcpf(x);
#else
  return 1.0f / x;
#endif
}
__device__ __forceinline__ float fast_exp2(float x) {
#if __has_builtin(__builtin_amdgcn_exp2f)
  return __builtin_amdgcn_exp2f(x);
#else
  return exp2f(x);
#endif
}

// Fused projections: z=0 -> exp(2*(X@W_X^T+b_X))^T, z=1 -> same for ref.
// 64(m) x 64(h) tile, K-chunk 32, grid (64,4,2), block 256, 4x4 microtile.
// v3: double-buffered LDS (1 barrier/chunk) + register fragment prefetch.
__global__ __launch_bounds__(256, 4) void proj_fused(
    const float* __restrict__ A0, const float* __restrict__ A1,
    const float* __restrict__ W0, const float* __restrict__ W1,
    const float* __restrict__ bias0, const float* __restrict__ bias1,
    float* __restrict__ E0, float* __restrict__ E1) {
  __shared__ float smem[2 * 4352];  // 2 bufs x (As[32][68] + Ws[32][68])
  const int K = CD;
  int z = blockIdx.z;
  const float* A = z ? A1 : A0;
  const float* W = z ? W1 : W0;
  const float* bias = z ? bias1 : bias0;
  float* ET = z ? E1 : E0;
  int m0 = blockIdx.x * 64, n0 = blockIdx.y * 64;
  int tid = threadIdx.x;
  int tx = tid & 15, ty = tid >> 4;  // tx -> h, ty -> m(x)
  int lrow = tid >> 2, lc4 = tid & 3;
  float acc[4][4] = {};
  const float* pA = A + (size_t)(m0 + lrow) * K + lc4 * 4;
  const float* pW = W + (size_t)(n0 + lrow) * K + lc4 * 4;
  float4 av0 = *(const float4*)(pA);
  float4 av1 = *(const float4*)(pA + 16);
  float4 wv0 = *(const float4*)(pW);
  float4 wv1 = *(const float4*)(pW + 16);
  {
    float* As = smem;
    float* Ws = smem + 2176;
    As[(lc4 * 4 + 0) * 68 + lrow] = av0.x;
    As[(lc4 * 4 + 1) * 68 + lrow] = av0.y;
    As[(lc4 * 4 + 2) * 68 + lrow] = av0.z;
    As[(lc4 * 4 + 3) * 68 + lrow] = av0.w;
    As[(lc4 * 4 + 16) * 68 + lrow] = av1.x;
    As[(lc4 * 4 + 17) * 68 + lrow] = av1.y;
    As[(lc4 * 4 + 18) * 68 + lrow] = av1.z;
    As[(lc4 * 4 + 19) * 68 + lrow] = av1.w;
    Ws[(lc4 * 4 + 0) * 68 + lrow] = wv0.x;
    Ws[(lc4 * 4 + 1) * 68 + lrow] = wv0.y;
    Ws[(lc4 * 4 + 2) * 68 + lrow] = wv0.z;
    Ws[(lc4 * 4 + 3) * 68 + lrow] = wv0.w;
    Ws[(lc4 * 4 + 16) * 68 + lrow] = wv1.x;
    Ws[(lc4 * 4 + 17) * 68 + lrow] = wv1.y;
    Ws[(lc4 * 4 + 18) * 68 + lrow] = wv1.z;
    Ws[(lc4 * 4 + 19) * 68 + lrow] = wv1.w;
  }
  for (int c = 0; c < 8; c++) {
    __syncthreads();
    if (c < 7) {
      int kt = (c + 1) * 32;
      av0 = *(const float4*)(pA + kt);
      av1 = *(const float4*)(pA + kt + 16);
      wv0 = *(const float4*)(pW + kt);
      wv1 = *(const float4*)(pW + kt + 16);
    }
    const float* As = smem + (c & 1) * 4352;
    const float* Ws = As + 2176;
    float4 fa[2], fw[2];
    fa[0] = *(const float4*)&As[ty * 4];
    fw[0] = *(const float4*)&Ws[tx * 4];
#pragma unroll
    for (int k = 0; k < 32; k++) {
      int cur = k & 1;
      if (k < 31) {
        fa[cur ^ 1] = *(const float4*)&As[(k + 1) * 68 + ty * 4];
        fw[cur ^ 1] = *(const float4*)&Ws[(k + 1) * 68 + tx * 4];
      }
      float am[4] = {fa[cur].x, fa[cur].y, fa[cur].z, fa[cur].w};
      float wm[4] = {fw[cur].x, fw[cur].y, fw[cur].z, fw[cur].w};
#pragma unroll
      for (int i = 0; i < 4; i++)
#pragma unroll
        for (int j = 0; j < 4; j++)
          acc[i][j] = fmaf(am[i], wm[j], acc[i][j]);
    }
    if (c < 7) {
      float* Asw = smem + ((c + 1) & 1) * 4352;
      float* Wsw = Asw + 2176;
      Asw[(lc4 * 4 + 0) * 68 + lrow] = av0.x;
      Asw[(lc4 * 4 + 1) * 68 + lrow] = av0.y;
      Asw[(lc4 * 4 + 2) * 68 + lrow] = av0.z;
      Asw[(lc4 * 4 + 3) * 68 + lrow] = av0.w;
      Asw[(lc4 * 4 + 16) * 68 + lrow] = av1.x;
      Asw[(lc4 * 4 + 17) * 68 + lrow] = av1.y;
      Asw[(lc4 * 4 + 18) * 68 + lrow] = av1.z;
      Asw[(lc4 * 4 + 19) * 68 + lrow] = av1.w;
      Wsw[(lc4 * 4 + 0) * 68 + lrow] = wv0.x;
      Wsw[(lc4 * 4 + 1) * 68 + lrow] = wv0.y;
      Wsw[(lc4 * 4 + 2) * 68 + lrow] = wv0.z;
      Wsw[(lc4 * 4 + 3) * 68 + lrow] = wv0.w;
      Wsw[(lc4 * 4 + 16) * 68 + lrow] = wv1.x;
      Wsw[(lc4 * 4 + 17) * 68 + lrow] = wv1.y;
      Wsw[(lc4 * 4 + 18) * 68 + lrow] = wv1.z;
      Wsw[(lc4 * 4 + 19) * 68 + lrow] = wv1.w;
    }
  }
  const float K2L = 2.8853900817779268f;  // 2*log2(e)
  float4 bv = *(const float4*)(bias + n0 + tx * 4);
  float bm[4] = {bv.x, bv.y, bv.z, bv.w};
  int b = m0 >> 9;
  int xbase = (m0 & 511) + ty * 4;
#pragma unroll
  for (int j = 0; j < 4; j++) {
    int h = n0 + tx * 4 + j;
    float4 o = {fast_exp2(K2L * (acc[0][j] + bm[j])),
                fast_exp2(K2L * (acc[1][j] + bm[j])),
                fast_exp2(K2L * (acc[2][j] + bm[j])),
                fast_exp2(K2L * (acc[3][j] + bm[j]))};
    *(float4*)(ET + ((size_t)b * CH + h) * CNX + xbase) = o;
  }
}

// scT[b][r][x] = sum_h (-2*v_w[h]) / (exT[b][h][x]*erT[b][h][r] + 1)
// 64(x) x 64(r) tile, grid (8,8,8), block 512 = two 256-thread groups
// h-splitting the reduction. v3: double-buffered LDS (1 barrier/chunk,
// 32-h chunks) + register fragment prefetch in the hq loop.
__global__ __launch_bounds__(512, 4) void scores_kernel(
    const float* __restrict__ exT, const float* __restrict__ erT,
    const float* __restrict__ v_w, float* __restrict__ scT) {
  // per group: 2 bufs x (xs[32][64] + rs[32][64]) = 8192 floats; + vsh
  __shared__ float smem[2 * 8192 + 256];
  int b = blockIdx.z;
  int x0 = blockIdx.x * 64, r0 = blockIdx.y * 64;
  int tid = threadIdx.x;
  int g = tid >> 8, t = tid & 255;
  float* base = smem + g * 8192;
  float* vsh = smem + 16384;
  if (tid < 256) vsh[tid] = -2.0f * v_w[tid];
  int tx = t & 15, ty = t >> 4;
  int sr = t >> 4, sc = (t & 15) * 4;
  const float* pX = exT + (size_t)b * CH * CNX + x0 + sc;
  const float* pR = erT + (size_t)b * CH * CNR + r0 + sc;
  int hb = g * 32;
  float4 xa0 = *(const float4*)(pX + (size_t)(hb + sr) * CNX);
  float4 xa1 = *(const float4*)(pX + (size_t)(hb + sr + 16) * CNX);
  float4 ra0 = *(const float4*)(pR + (size_t)(hb + sr) * CNR);
  float4 ra1 = *(const float4*)(pR + (size_t)(hb + sr + 16) * CNR);
  {
    float* xs = base;
    float* rs = base + 2048;
    *(float4*)&xs[sr * 64 + sc] = xa0;
    *(float4*)&xs[(sr + 16) * 64 + sc] = xa1;
    *(float4*)&rs[sr * 64 + sc] = ra0;
    *(float4*)&rs[(sr + 16) * 64 + sc] = ra1;
  }
  float acc[4][4] = {};
  for (int c = 0; c < 4; c++) {
    __syncthreads();
    int hc = hb + c * 64;  // this group's chunk: h in [hc, hc+32)
    if (c < 3) {
      int hn = hc + 64;
      xa0 = *(const float4*)(pX + (size_t)(hn + sr) * CNX);
      xa1 = *(const float4*)(pX + (size_t)(hn + sr + 16) * CNX);
      ra0 = *(const float4*)(pR + (size_t)(hn + sr) * CNR);
      ra1 = *(const float4*)(pR + (size_t)(hn + sr + 16) * CNR);
    }
    const float* xs = base + (c & 1) * 4096;
    const float* rs = xs + 2048;
    float4 fx[2][4], fr[2][4];
#pragma unroll
    for (int q = 0; q < 4; q++) {
      fx[0][q] = *(const float4*)&xs[q * 64 + tx * 4];
      fr[0][q] = *(const float4*)&rs[q * 64 + ty * 4];
    }
#pragma unroll
    for (int hq = 0; hq < 8; hq++) {
      int cur = hq & 1, nxt = cur ^ 1;
      if (hq < 7) {
        int h1 = (hq + 1) * 4;
#pragma unroll
        for (int q = 0; q < 4; q++) {
          fx[nxt][q] = *(const float4*)&xs[(h1 + q) * 64 + tx * 4];
          fr[nxt][q] = *(const float4*)&rs[(h1 + q) * 64 + ty * 4];
        }
      }
      float4 vv = *(const float4*)&vsh[hc + hq * 4];
      float xm0[4] = {fx[cur][0].x, fx[cur][0].y, fx[cur][0].z, fx[cur][0].w};
      float xm1[4] = {fx[cur][1].x, fx[cur][1].y, fx[cur][1].z, fx[cur][1].w};
      float xm2[4] = {fx[cur][2].x, fx[cur][2].y, fx[cur][2].z, fx[cur][2].w};
      float xm3[4] = {fx[cur][3].x, fx[cur][3].y, fx[cur][3].z, fx[cur][3].w};
      float rm0[4] = {fr[cur][0].x, fr[cur][0].y, fr[cur][0].z, fr[cur][0].w};
      float rm1[4] = {fr[cur][1].x, fr[cur][1].y, fr[cur][1].z, fr[cur][1].w};
      float rm2[4] = {fr[cur][2].x, fr[cur][2].y, fr[cur][2].z, fr[cur][2].w};
      float rm3[4] = {fr[cur][3].x, fr[cur][3].y, fr[cur][3].z, fr[cur][3].w};
#pragma unroll
      for (int i = 0; i < 4; i++)
#pragma unroll
        for (int j = 0; j < 4; j++) {
          float a = fmaf(rm0[i], xm0[j], 1.0f);
          float bb = fmaf(rm1[i], xm1[j], 1.0f);
          float cc = fmaf(rm2[i], xm2[j], 1.0f);
          float dd = fmaf(rm3[i], xm3[j], 1.0f);
          float q12 = a * bb, q34 = cc * dd;
          float p12 = fmaf(vv.y, a, vv.x * bb);
          float p34 = fmaf(vv.w, cc, vv.z * dd);
          float num = fmaf(p34, q12, p12 * q34);
          acc[i][j] = fmaf(num, fast_rcp(q12 * q34), acc[i][j]);
        }
    }
    if (c < 3) {
      float* xw = base + ((c + 1) & 1) * 4096;
      float* rw = xw + 2048;
      *(float4*)&xw[sr * 64 + sc] = xa0;
      *(float4*)&xw[(sr + 16) * 64 + sc] = xa1;
      *(float4*)&rw[sr * 64 + sc] = ra0;
      *(float4*)&rw[(sr + 16) * 64 + sc] = ra1;
    }
  }
  __syncthreads();
  float* mg = smem;
  if (g == 1) {
#pragma unroll
    for (int i = 0; i < 4; i++)
#pragma unroll
      for (int j = 0; j < 4; j++)
        mg[t + 256 * (i * 4 + j)] = acc[i][j];
  }
  __syncthreads();
  if (g == 0) {
    float* pO = scT + ((size_t)b * CNR + r0 + ty * 4) * CNX + x0 + tx * 4;
#pragma unroll
    for (int i = 0; i < 4; i++) {
      float4 o = {acc[i][0] + mg[t + 256 * (i * 4 + 0)],
                  acc[i][1] + mg[t + 256 * (i * 4 + 1)],
                  acc[i][2] + mg[t + 256 * (i * 4 + 2)],
                  acc[i][3] + mg[t + 256 * (i * 4 + 3)]};
      *(float4*)(pO + (size_t)i * CNX) = o;
    }
  }
}

// Fused softmax + weighted sum. out[b][r][d] = sum_x e(b,r,x)*X[b][x][d] / sum_x e
// 64(r) x 64(d) tile, grid (8,4,8)=256 blocks, block 1024 = FOUR 256-thread
// groups splitting K (16 waves/CU). v3: double-buffered LDS (1 barrier per
// 32-k chunk) + register fragment prefetch. LDS 129 KB static.
__global__ __launch_bounds__(1024, 4) void wsum_fused(
    const float* __restrict__ scT, const float* __restrict__ X,
    float* __restrict__ out) {
  // per group: 2 bufs x (As[32][64] + Bs[32][64]) = 8192 floats; + dnn[256]
  __shared__ float smem[4 * 8192 + 256];
  const float L2E = 1.4426950408889634f;
  int b = blockIdx.z;
  int r0 = blockIdx.x * 64, d0 = blockIdx.y * 64;
  int tid = threadIdx.x;
  int g = tid >> 8, t = tid & 255;
  float* base = smem + g * 8192;
  float* dnn = smem + 32768;
  int tx = t & 15, ty = t >> 4;        // tx -> d(4), ty -> r(4)
  int ar = t >> 2, ak = (t & 3) * 4;   // scT staging: row ar, k ak..+3, +16
  int br = t >> 4, bc = (t & 15) * 4;  // X staging: k-rows br, br+16; d col bc
  int kb = g * 32;
  const float* pS = scT + ((size_t)b * CNR + r0 + ar) * CNX + ak;
  const float* pB = X + (size_t)b * CNX * CD + d0 + bc;
  float acc[4][4] = {};
  float dsum = 0.0f;
  float4 s0 = *(const float4*)(pS + kb);
  float4 s1 = *(const float4*)(pS + kb + 16);
  float4 b0 = *(const float4*)(pB + (size_t)(kb + br) * CD);
  float4 b1 = *(const float4*)(pB + (size_t)(kb + br + 16) * CD);
  {
    float* As = base;
    float* Bs = base + 2048;
    float4 e0 = {fast_exp2(s0.x * L2E), fast_exp2(s0.y * L2E),
                 fast_exp2(s0.z * L2E), fast_exp2(s0.w * L2E)};
    float4 e1 = {fast_exp2(s1.x * L2E), fast_exp2(s1.y * L2E),
                 fast_exp2(s1.z * L2E), fast_exp2(s1.w * L2E)};
    dsum += ((e0.x + e0.y) + (e0.z + e0.w)) + ((e1.x + e1.y) + (e1.z + e1.w));
    As[(ak + 0) * 64 + ar] = e0.x;
    As[(ak + 1) * 64 + ar] = e0.y;
    As[(ak + 2) * 64 + ar] = e0.z;
    As[(ak + 3) * 64 + ar] = e0.w;
    As[(ak + 16) * 64 + ar] = e1.x;
    As[(ak + 17) * 64 + ar] = e1.y;
    As[(ak + 18) * 64 + ar] = e1.z;
    As[(ak + 19) * 64 + ar] = e1.w;
    *(float4*)&Bs[br * 64 + bc] = b0;
    *(float4*)&Bs[(br + 16) * 64 + bc] = b1;
  }
  for (int c = 0; c < 4; c++) {
    __syncthreads();
    if (c < 3) {
      int kn = kb + (c + 1) * 128;
      s0 = *(const float4*)(pS + kn);
      s1 = *(const float4*)(pS + kn + 16);
      b0 = *(const float4*)(pB + (size_t)(kn + br) * CD);
      b1 = *(const float4*)(pB + (size_t)(kn + br + 16) * CD);
    }
    const float* As = base + (c & 1) * 4096;
    const float* Bs = As + 2048;
    float4 fa[2], fb[2];
    fa[0] = *(const float4*)&As[ty * 4];
    fb[0] = *(const float4*)&Bs[tx * 4];
#pragma unroll
    for (int k = 0; k < 32; k++) {
      int cur = k & 1;
      if (k < 31) {
        fa[cur ^ 1] = *(const float4*)&As[(k + 1) * 64 + ty * 4];
        fb[cur ^ 1] = *(const float4*)&Bs[(k + 1) * 64 + tx * 4];
      }
      float am[4] = {fa[cur].x, fa[cur].y, fa[cur].z, fa[cur].w};
      float bm[4] = {fb[cur].x, fb[cur].y, fb[cur].z, fb[cur].w};
#pragma unroll
      for (int i = 0; i < 4; i++)
#pragma unroll
        for (int j = 0; j < 4; j++)
          acc[i][j] = fmaf(am[i], bm[j], acc[i][j]);
    }
    if (c < 3) {
      float* Asw = base + ((c + 1) & 1) * 4096;
      float* Bsw = Asw + 2048;
      float4 e0 = {fast_exp2(s0.x * L2E), fast_exp2(s0.y * L2E),
                   fast_exp2(s0.z * L2E), fast_exp2(s0.w * L2E)};
      float4 e1 = {fast_exp2(s1.x * L2E), fast_exp2(s1.y * L2E),
                   fast_exp2(s1.z * L2E), fast_exp2(s1.w * L2E)};
      dsum += ((e0.x + e0.y) + (e0.z + e0.w)) + ((e1.x + e1.y) + (e1.z + e1.w));
      Asw[(ak + 0) * 64 + ar] = e0.x;
      Asw[(ak + 1) * 64 + ar] = e0.y;
      Asw[(ak + 2) * 64 + ar] = e0.z;
      Asw[(ak + 3) * 64 + ar] = e0.w;
      Asw[(ak + 16) * 64 + ar] = e1.x;
      Asw[(ak + 17) * 64 + ar] = e1.y;
      Asw[(ak + 18) * 64 + ar] = e1.z;
      Asw[(ak + 19) * 64 + ar] = e1.w;
      *(float4*)&Bsw[br * 64 + bc] = b0;
      *(float4*)&Bsw[(br + 16) * 64 + bc] = b1;
    }
  }
  // denominator partial: 4 lanes (t&3) share row ar
  dsum += __shfl_xor(dsum, 1, 64);
  dsum += __shfl_xor(dsum, 2, 64);
  if ((t & 3) == 0) dnn[g * 64 + ar] = dsum;
  __syncthreads();
  float* mg = smem;  // 3 x 4096 floats of partials (groups 1..3)
  if (g > 0) {
#pragma unroll
    for (int i = 0; i < 4; i++)
#pragma unroll
      for (int j = 0; j < 4; j++)
        mg[(g - 1) * 4096 + 256 * (i * 4 + j) + t] = acc[i][j];
  }
  __syncthreads();
  if (g == 0) {
    float invm[4];
#pragma unroll
    for (int i = 0; i < 4; i++) {
      int rr = ty * 4 + i;
      invm[i] = fast_rcp(dnn[rr] + dnn[64 + rr] + dnn[128 + rr] + dnn[192 + rr]);
    }
    float* pO = out + ((size_t)b * CNR + r0 + ty * 4) * CD + d0 + tx * 4;
#pragma unroll
    for (int i = 0; i < 4; i++) {
      float s[4];
#pragma unroll
      for (int j = 0; j < 4; j++) {
        int o = 256 * (i * 4 + j) + t;
        s[j] = (acc[i][j] + mg[o] + mg[4096 + o] + mg[8192 + o]) * invm[i];
      }
      float4 o4 = {s[0], s[1], s[2], s[3]};
      *(float4*)(pO + (size_t)i * CD) = o4;
    }
  }
}

extern "C" void kernel_launch(void* const* d_in, const int* in_sizes, int n_in,
                              void* d_out, int out_size, void* d_ws, size_t ws_size,
                              hipStream_t stream) {
  const float* X     = (const float*)d_in[0];
  const float* ref   = (const float*)d_in[1];
  const float* W_X   = (const float*)d_in[2];
  const float* b_X   = (const float*)d_in[3];
  const float* W_ref = (const float*)d_in[4];
  const float* b_ref = (const float*)d_in[5];
  const float* v_w   = (const float*)d_in[6];
  float* out = (float*)d_out;
  float* ws  = (float*)d_ws;

  float* exT = ws;                       // [B][H][NX] = 1,048,576 floats
  float* erT = ws + 1048576;             // [B][H][NR] = 1,048,576 floats
  float* scT = ws + 2097152;             // [B][NR][NX] = 2,097,152 floats

  proj_fused<<<dim3(64, 4, 2), 256, 0, stream>>>(X, ref, W_X, W_ref, b_X, b_ref, exT, erT);
  scores_kernel<<<dim3(8, 8, 8), 512, 0, stream>>>(exT, erT, v_w, scT);
  wsum_fused<<<dim3(8, 4, 8), 1024, 0, stream>>>(scT, X, out);
}

// Round 4
// 152.790 us; speedup vs baseline: 10.1461x; 10.1461x over previous
//
#include <hip/hip_runtime.h>
#include <math.h>

#define CB 8
#define CNX 512
#define CNR 512
#define CD 256
#define CH 256

__device__ __forceinline__ float fast_rcp(float x) {
#if __has_builtin(__builtin_amdgcn_rcpf)
  return __builtin_amdgcn_rcpf(x);
#else
  return 1.0f / x;
#endif
}
__device__ __forceinline__ float fast_exp2(float x) {
#if __has_builtin(__builtin_amdgcn_exp2f)
  return __builtin_amdgcn_exp2f(x);
#else
  return exp2f(x);
#endif
}

// Fused projections: z=0 -> exp(2*(X@W_X^T+b_X))^T, z=1 -> same for ref.
// ET[b][h][x] = exp2(K2L*(sum_k A[m][k]*W[h][k] + bias[h])), m=b*512+x
// 64(m) x 64(h) tile, K-tile 16, grid (64,4,2), block 256, 4x4 microtile.
// v4: per-wave k-rotation desynchronizes LDS read bursts across waves.
__global__ __launch_bounds__(256) void proj_fused(
    const float* __restrict__ A0, const float* __restrict__ A1,
    const float* __restrict__ W0, const float* __restrict__ W1,
    const float* __restrict__ bias0, const float* __restrict__ bias1,
    float* __restrict__ E0, float* __restrict__ E1) {
  __shared__ float As[16][68];  // [k][m] padded
  __shared__ float Ws[16][68];  // [k][h] padded
  const int K = CD;
  int z = blockIdx.z;
  const float* A = z ? A1 : A0;
  const float* W = z ? W1 : W0;
  const float* bias = z ? bias1 : bias0;
  float* ET = z ? E1 : E0;
  int m0 = blockIdx.x * 64, n0 = blockIdx.y * 64;
  int tid = threadIdx.x;
  int tx = tid & 15, ty = tid >> 4;  // tx -> h, ty -> m(x)
  int lrow = tid >> 2, lc4 = tid & 3;
  int krot = (tid >> 6) << 2;  // wave 0..3 -> rotate k by 0,4,8,12
  float acc[4][4] = {};
  const float* pA = A + (size_t)(m0 + lrow) * K + lc4 * 4;
  const float* pW = W + (size_t)(n0 + lrow) * K + lc4 * 4;
  float4 av = *(const float4*)(pA);
  float4 wv = *(const float4*)(pW);
  for (int kt = 0; kt < K; kt += 16) {
    __syncthreads();
    As[lc4 * 4 + 0][lrow] = av.x;
    As[lc4 * 4 + 1][lrow] = av.y;
    As[lc4 * 4 + 2][lrow] = av.z;
    As[lc4 * 4 + 3][lrow] = av.w;
    Ws[lc4 * 4 + 0][lrow] = wv.x;
    Ws[lc4 * 4 + 1][lrow] = wv.y;
    Ws[lc4 * 4 + 2][lrow] = wv.z;
    Ws[lc4 * 4 + 3][lrow] = wv.w;
    __syncthreads();
    if (kt + 16 < K) {
      av = *(const float4*)(pA + kt + 16);
      wv = *(const float4*)(pW + kt + 16);
    }
#pragma unroll
    for (int k = 0; k < 16; k++) {
      int kk = (k + krot) & 15;
      float4 a4 = *(const float4*)&As[kk][ty * 4];
      float4 w4 = *(const float4*)&Ws[kk][tx * 4];
      float am[4] = {a4.x, a4.y, a4.z, a4.w};
      float wm[4] = {w4.x, w4.y, w4.z, w4.w};
#pragma unroll
      for (int i = 0; i < 4; i++)
#pragma unroll
        for (int j = 0; j < 4; j++)
          acc[i][j] = fmaf(am[i], wm[j], acc[i][j]);
    }
  }
  const float K2L = 2.8853900817779268f;  // 2*log2(e)
  float4 bv = *(const float4*)(bias + n0 + tx * 4);
  float bm[4] = {bv.x, bv.y, bv.z, bv.w};
  int b = m0 >> 9;
  int xbase = (m0 & 511) + ty * 4;
#pragma unroll
  for (int j = 0; j < 4; j++) {
    int h = n0 + tx * 4 + j;
    float4 o = {fast_exp2(K2L * (acc[0][j] + bm[j])),
                fast_exp2(K2L * (acc[1][j] + bm[j])),
                fast_exp2(K2L * (acc[2][j] + bm[j])),
                fast_exp2(K2L * (acc[3][j] + bm[j]))};
    *(float4*)(ET + ((size_t)b * CH + h) * CNX + xbase) = o;
  }
}

// scT[b][r][x] = -2 * sum_h v_w[h] / (exT[b][h][x]*erT[b][h][r] + 1)
// 64(x) x 64(r) tile, grid (8,8,8)=512 blocks, block 512 (two 256-thread
// groups h-splitting the reduction), 4x4 microtile, LDS partial-merge.
// v4: per-wave hq-rotation desynchronizes LDS read bursts across waves.
__global__ __launch_bounds__(512) void scores_kernel(
    const float* __restrict__ exT, const float* __restrict__ erT,
    const float* __restrict__ v_w, float* __restrict__ scT) {
  // layout: xs0[32*64] rs0[32*64] xs1[32*64] rs1[32*64] vsh[256]
  __shared__ float smem[4 * 2048 + 256];
  int b = blockIdx.z;
  int x0 = blockIdx.x * 64, r0 = blockIdx.y * 64;
  int tid = threadIdx.x;
  int g = tid >> 8;      // reduction group
  int t = tid & 255;
  float* xs = smem + g * 4096;   // [32][64]
  float* rs = xs + 2048;         // [32][64]
  float* vsh = smem + 8192;
  if (tid < 256) vsh[tid] = v_w[tid];
  int tx = t & 15, ty = t >> 4;  // tx -> x(4), ty -> r(4)
  int sr = t >> 4, sc = (t & 15) * 4;  // staging: 16 rows x 16 float4
  int wrot = (tid >> 6) & 7;     // 8 waves -> rotate hq by 0..7
  const float* pX = exT + (size_t)b * CH * CNX + x0 + sc;
  const float* pR = erT + (size_t)b * CH * CNR + r0 + sc;
  int hb = g * 32;
  float4 xa0 = *(const float4*)(pX + (size_t)(hb + sr) * CNX);
  float4 xa1 = *(const float4*)(pX + (size_t)(hb + sr + 16) * CNX);
  float4 ra0 = *(const float4*)(pR + (size_t)(hb + sr) * CNR);
  float4 ra1 = *(const float4*)(pR + (size_t)(hb + sr + 16) * CNR);
  float acc[4][4] = {};
  for (int hc = hb; hc < CH; hc += 64) {
    __syncthreads();
    *(float4*)&xs[sr * 64 + sc] = xa0;
    *(float4*)&xs[(sr + 16) * 64 + sc] = xa1;
    *(float4*)&rs[sr * 64 + sc] = ra0;
    *(float4*)&rs[(sr + 16) * 64 + sc] = ra1;
    __syncthreads();
    if (hc + 64 < CH) {
      xa0 = *(const float4*)(pX + (size_t)(hc + 64 + sr) * CNX);
      xa1 = *(const float4*)(pX + (size_t)(hc + 64 + sr + 16) * CNX);
      ra0 = *(const float4*)(pR + (size_t)(hc + 64 + sr) * CNR);
      ra1 = *(const float4*)(pR + (size_t)(hc + 64 + sr + 16) * CNR);
    }
#pragma unroll 2
    for (int hq = 0; hq < 8; hq++) {
      int h0 = ((hq + wrot) & 7) * 4;
      float4 vv = *(const float4*)&vsh[hc + h0];
      float4 xv0 = *(const float4*)&xs[(h0 + 0) * 64 + tx * 4];
      float4 xv1 = *(const float4*)&xs[(h0 + 1) * 64 + tx * 4];
      float4 xv2 = *(const float4*)&xs[(h0 + 2) * 64 + tx * 4];
      float4 xv3 = *(const float4*)&xs[(h0 + 3) * 64 + tx * 4];
      float4 rv0 = *(const float4*)&rs[(h0 + 0) * 64 + ty * 4];
      float4 rv1 = *(const float4*)&rs[(h0 + 1) * 64 + ty * 4];
      float4 rv2 = *(const float4*)&rs[(h0 + 2) * 64 + ty * 4];
      float4 rv3 = *(const float4*)&rs[(h0 + 3) * 64 + ty * 4];
      float xm0[4] = {xv0.x, xv0.y, xv0.z, xv0.w};
      float xm1[4] = {xv1.x, xv1.y, xv1.z, xv1.w};
      float xm2[4] = {xv2.x, xv2.y, xv2.z, xv2.w};
      float xm3[4] = {xv3.x, xv3.y, xv3.z, xv3.w};
      float rm0[4] = {rv0.x, rv0.y, rv0.z, rv0.w};
      float rm1[4] = {rv1.x, rv1.y, rv1.z, rv1.w};
      float rm2[4] = {rv2.x, rv2.y, rv2.z, rv2.w};
      float rm3[4] = {rv3.x, rv3.y, rv3.z, rv3.w};
#pragma unroll
      for (int i = 0; i < 4; i++)
#pragma unroll
        for (int j = 0; j < 4; j++) {
          float a = fmaf(rm0[i], xm0[j], 1.0f);
          float bb = fmaf(rm1[i], xm1[j], 1.0f);
          float c = fmaf(rm2[i], xm2[j], 1.0f);
          float d = fmaf(rm3[i], xm3[j], 1.0f);
          float q12 = a * bb, q34 = c * d;
          float p12 = fmaf(vv.y, a, vv.x * bb);
          float p34 = fmaf(vv.w, c, vv.z * d);
          float num = fmaf(p34, q12, p12 * q34);
          acc[i][j] = fmaf(num, fast_rcp(q12 * q34), acc[i][j]);
        }
    }
  }
  // merge the two h-partials (reuse smem[0..4096) after barrier)
  __syncthreads();
  float* mg = smem;
  if (g == 1) {
#pragma unroll
    for (int i = 0; i < 4; i++)
#pragma unroll
      for (int j = 0; j < 4; j++)
        mg[t + 256 * (i * 4 + j)] = acc[i][j];
  }
  __syncthreads();
  if (g == 0) {
    float* pO = scT + ((size_t)b * CNR + r0 + ty * 4) * CNX + x0 + tx * 4;
#pragma unroll
    for (int i = 0; i < 4; i++) {
      float4 o = {-2.0f * (acc[i][0] + mg[t + 256 * (i * 4 + 0)]),
                  -2.0f * (acc[i][1] + mg[t + 256 * (i * 4 + 1)]),
                  -2.0f * (acc[i][2] + mg[t + 256 * (i * 4 + 2)]),
                  -2.0f * (acc[i][3] + mg[t + 256 * (i * 4 + 3)])};
      *(float4*)(pO + (size_t)i * CNX) = o;
    }
  }
}

// Fused softmax + weighted sum. Scores bounded so unnormalized exp(s) is
// fp32-safe; numerator and denominator in one K-loop.
// out[b][r][d] = sum_x e(b,r,x)*X[b][x][d] / sum_x e(b,r,x)
// 64(r) x 64(d) tile, grid (8,4,8)=256 blocks, block 512 (two 256-thread
// groups x-splitting the K loop), 4x4 microtile, register prefetch.
// v4: per-wave k-rotation desynchronizes LDS read bursts across waves.
__global__ __launch_bounds__(512) void wsum_fused(
    const float* __restrict__ scT, const float* __restrict__ X,
    float* __restrict__ out) {
  // layout: As0[32*68] Bs0[32*68] As1[32*68] Bs1[32*68] dn[128]
  __shared__ float smem[4 * 2176 + 128];
  const float L2E = 1.4426950408889634f;
  int b = blockIdx.z;
  int r0 = blockIdx.x * 64, d0 = blockIdx.y * 64;
  int tid = threadIdx.x;
  int g = tid >> 8;
  int t = tid & 255;
  float* As = smem + g * 4352;   // [32][68] [k][r]
  float* Bs = As + 2176;         // [32][68] [k][d]
  float* dnn = smem + 8704;      // [2][64]
  int tx = t & 15, ty = t >> 4;        // tx -> d(4), ty -> r(4)
  int ar = t >> 2, ak = (t & 3) * 4;   // scT: 64 r-rows, k = ak..ak+3, +16
  int br = t >> 4, bc = (t & 15) * 4;  // X: k-rows br, br+16; d cols bc
  int krot = ((tid >> 6) & 7) * 4;     // 8 waves -> rotate k by 0,4,..,28
  int kb = g * 32;
  const float* pS = scT + ((size_t)b * CNR + r0 + ar) * CNX + ak;
  const float* pB = X + (size_t)b * CNX * CD + d0 + bc;
  float acc[4][4] = {};
  float dsum = 0.0f;
  float4 s0 = *(const float4*)(pS + kb);
  float4 s1 = *(const float4*)(pS + kb + 16);
  float4 b0 = *(const float4*)(pB + (size_t)(kb + br) * CD);
  float4 b1 = *(const float4*)(pB + (size_t)(kb + br + 16) * CD);
  for (int kt = kb; kt < CNX; kt += 64) {
    float4 e0 = {fast_exp2(s0.x * L2E), fast_exp2(s0.y * L2E),
                 fast_exp2(s0.z * L2E), fast_exp2(s0.w * L2E)};
    float4 e1 = {fast_exp2(s1.x * L2E), fast_exp2(s1.y * L2E),
                 fast_exp2(s1.z * L2E), fast_exp2(s1.w * L2E)};
    dsum += ((e0.x + e0.y) + (e0.z + e0.w)) + ((e1.x + e1.y) + (e1.z + e1.w));
    __syncthreads();
    As[(ak + 0) * 68 + ar] = e0.x;
    As[(ak + 1) * 68 + ar] = e0.y;
    As[(ak + 2) * 68 + ar] = e0.z;
    As[(ak + 3) * 68 + ar] = e0.w;
    As[(ak + 16) * 68 + ar] = e1.x;
    As[(ak + 17) * 68 + ar] = e1.y;
    As[(ak + 18) * 68 + ar] = e1.z;
    As[(ak + 19) * 68 + ar] = e1.w;
    *(float4*)&Bs[br * 68 + bc] = b0;
    *(float4*)&Bs[(br + 16) * 68 + bc] = b1;
    __syncthreads();
    if (kt + 64 < CNX) {
      s0 = *(const float4*)(pS + kt + 64);
      s1 = *(const float4*)(pS + kt + 80);
      b0 = *(const float4*)(pB + (size_t)(kt + 64 + br) * CD);
      b1 = *(const float4*)(pB + (size_t)(kt + 64 + br + 16) * CD);
    }
#pragma unroll 8
    for (int k = 0; k < 32; k++) {
      int kk = (k + krot) & 31;
      float4 a4 = *(const float4*)&As[kk * 68 + ty * 4];
      float4 b4 = *(const float4*)&Bs[kk * 68 + tx * 4];
      float am[4] = {a4.x, a4.y, a4.z, a4.w};
      float bm[4] = {b4.x, b4.y, b4.z, b4.w};
#pragma unroll
      for (int i = 0; i < 4; i++)
#pragma unroll
        for (int j = 0; j < 4; j++)
          acc[i][j] = fmaf(am[i], bm[j], acc[i][j]);
    }
  }
  // denominator partial: 4 lanes (t&3) share row ar
  dsum += __shfl_xor(dsum, 1, 64);
  dsum += __shfl_xor(dsum, 2, 64);
  if ((t & 3) == 0) dnn[g * 64 + ar] = dsum;
  __syncthreads();
  // merge the two x-partials (reuse smem[0..4096) after barrier; dn is safe)
  float* mg = smem;
  if (g == 1) {
#pragma unroll
    for (int i = 0; i < 4; i++)
#pragma unroll
      for (int j = 0; j < 4; j++)
        mg[t + 256 * (i * 4 + j)] = acc[i][j];
  }
  __syncthreads();
  if (g == 0) {
    float invm[4];
#pragma unroll
    for (int i = 0; i < 4; i++)
      invm[i] = fast_rcp(dnn[ty * 4 + i] + dnn[64 + ty * 4 + i]);
    float* pO = out + ((size_t)b * CNR + r0 + ty * 4) * CD + d0 + tx * 4;
#pragma unroll
    for (int i = 0; i < 4; i++) {
      float4 o = {
          (acc[i][0] + mg[t + 256 * (i * 4 + 0)]) * invm[i],
          (acc[i][1] + mg[t + 256 * (i * 4 + 1)]) * invm[i],
          (acc[i][2] + mg[t + 256 * (i * 4 + 2)]) * invm[i],
          (acc[i][3] + mg[t + 256 * (i * 4 + 3)]) * invm[i]};
      *(float4*)(pO + (size_t)i * CD) = o;
    }
  }
}

extern "C" void kernel_launch(void* const* d_in, const int* in_sizes, int n_in,
                              void* d_out, int out_size, void* d_ws, size_t ws_size,
                              hipStream_t stream) {
  const float* X     = (const float*)d_in[0];
  const float* ref   = (const float*)d_in[1];
  const float* W_X   = (const float*)d_in[2];
  const float* b_X   = (const float*)d_in[3];
  const float* W_ref = (const float*)d_in[4];
  const float* b_ref = (const float*)d_in[5];
  const float* v_w   = (const float*)d_in[6];
  float* out = (float*)d_out;
  float* ws  = (float*)d_ws;

  float* exT = ws;                       // [B][H][NX] = 1,048,576 floats
  float* erT = ws + 1048576;             // [B][H][NR] = 1,048,576 floats
  float* scT = ws + 2097152;             // [B][NR][NX] = 2,097,152 floats

  proj_fused<<<dim3(64, 4, 2), 256, 0, stream>>>(X, ref, W_X, W_ref, b_X, b_ref, exT, erT);
  scores_kernel<<<dim3(8, 8, 8), 512, 0, stream>>>(exT, erT, v_w, scT);
  wsum_fused<<<dim3(8, 4, 8), 512, 0, stream>>>(scT, X, out);
}

// Round 5
// 146.264 us; speedup vs baseline: 10.5988x; 1.0446x over previous
//
#include <hip/hip_runtime.h>
#include <math.h>

#define CB 8
#define CNX 512
#define CNR 512
#define CD 256
#define CH 256

typedef __attribute__((ext_vector_type(8))) short short8;
typedef __attribute__((ext_vector_type(4))) float f32x4;

__device__ __forceinline__ float fast_rcp(float x) {
#if __has_builtin(__builtin_amdgcn_rcpf)
  return __builtin_amdgcn_rcpf(x);
#else
  return 1.0f / x;
#endif
}
__device__ __forceinline__ float fast_exp2(float x) {
#if __has_builtin(__builtin_amdgcn_exp2f)
  return __builtin_amdgcn_exp2f(x);
#else
  return exp2f(x);
#endif
}

// Split a float into bf16 hi (truncation) + bf16 lo (residual, truncated),
// packing 8 consecutive k-values into uint4 hi and uint4 lo, store to LDS.
__device__ __forceinline__ void cvt_store(unsigned short* dstH,
                                          unsigned short* dstL,
                                          float4 v0, float4 v1) {
  unsigned u0x = __float_as_uint(v0.x), u0y = __float_as_uint(v0.y);
  unsigned u0z = __float_as_uint(v0.z), u0w = __float_as_uint(v0.w);
  unsigned u1x = __float_as_uint(v1.x), u1y = __float_as_uint(v1.y);
  unsigned u1z = __float_as_uint(v1.z), u1w = __float_as_uint(v1.w);
  uint4 H;
  H.x = (u0x >> 16) | (u0y & 0xFFFF0000u);
  H.y = (u0z >> 16) | (u0w & 0xFFFF0000u);
  H.z = (u1x >> 16) | (u1y & 0xFFFF0000u);
  H.w = (u1z >> 16) | (u1w & 0xFFFF0000u);
  float r0x = v0.x - __uint_as_float(u0x & 0xFFFF0000u);
  float r0y = v0.y - __uint_as_float(u0y & 0xFFFF0000u);
  float r0z = v0.z - __uint_as_float(u0z & 0xFFFF0000u);
  float r0w = v0.w - __uint_as_float(u0w & 0xFFFF0000u);
  float r1x = v1.x - __uint_as_float(u1x & 0xFFFF0000u);
  float r1y = v1.y - __uint_as_float(u1y & 0xFFFF0000u);
  float r1z = v1.z - __uint_as_float(u1z & 0xFFFF0000u);
  float r1w = v1.w - __uint_as_float(u1w & 0xFFFF0000u);
  uint4 L;
  L.x = (__float_as_uint(r0x) >> 16) | (__float_as_uint(r0y) & 0xFFFF0000u);
  L.y = (__float_as_uint(r0z) >> 16) | (__float_as_uint(r0w) & 0xFFFF0000u);
  L.z = (__float_as_uint(r1x) >> 16) | (__float_as_uint(r1y) & 0xFFFF0000u);
  L.w = (__float_as_uint(r1z) >> 16) | (__float_as_uint(r1w) & 0xFFFF0000u);
  *(uint4*)dstH = H;
  *(uint4*)dstL = L;
}

// Fused projections via split-bf16 MFMA (3 mfma: hi*hi + hi*lo + lo*hi).
// ET[b][h][x] = exp2(K2L*(sum_k A[m][k]*W[h][k] + bias[h])), m=b*512+x
// 64(m) x 64(h) tile, K-step 32, grid (64,4,2), block 256 = 4 waves,
// each wave a 32x32 quadrant (2x2 MFMA 16x16x32 frags). Double-buffered
// LDS (1 barrier/step), rows padded to 40 ushort (2-way bank alias, free).
__global__ __launch_bounds__(256) void proj_mfma(
    const float* __restrict__ A0, const float* __restrict__ A1,
    const float* __restrict__ W0, const float* __restrict__ W1,
    const float* __restrict__ bias0, const float* __restrict__ bias1,
    float* __restrict__ E0, float* __restrict__ E1) {
  // [buf][mat: Ah,Al,Wh,Wl][row][k] ; row stride 40 ushort = 80 B (16B mult)
  __shared__ unsigned short lds[2][4][64][40];
  const int K = CD;
  int z = blockIdx.z;
  const float* A = z ? A1 : A0;
  const float* W = z ? W1 : W0;
  const float* bias = z ? bias1 : bias0;
  float* ET = z ? E1 : E0;
  int m0 = blockIdx.x * 64, n0 = blockIdx.y * 64;
  int tid = threadIdx.x;
  int lane = tid & 63, w = tid >> 6;
  int wm = w >> 1, wn = w & 1;  // wave quadrant: m-half, n-half
  // staging: 64 rows x (4 threads/row x 8 k)
  int r = tid >> 2, kq = (tid & 3) * 8;
  const float* pA = A + (size_t)(m0 + r) * K + kq;
  const float* pW = W + (size_t)(n0 + r) * K + kq;
  f32x4 acc[2][2] = {};
  float4 a0 = *(const float4*)(pA);
  float4 a1 = *(const float4*)(pA + 4);
  float4 w0 = *(const float4*)(pW);
  float4 w1 = *(const float4*)(pW + 4);
  cvt_store(&lds[0][0][r][kq], &lds[0][1][r][kq], a0, a1);
  cvt_store(&lds[0][2][r][kq], &lds[0][3][r][kq], w0, w1);
  for (int s = 0; s < 8; s++) {
    __syncthreads();
    if (s < 7) {
      int kt = (s + 1) * 32;
      a0 = *(const float4*)(pA + kt);
      a1 = *(const float4*)(pA + kt + 4);
      w0 = *(const float4*)(pW + kt);
      w1 = *(const float4*)(pW + kt + 4);
    }
    int cur = s & 1;
    int arow = wm * 32 + (lane & 15);
    int brow = wn * 32 + (lane & 15);
    int koff = (lane >> 4) * 8;
    short8 ah0 = *(const short8*)&lds[cur][0][arow][koff];
    short8 ah1 = *(const short8*)&lds[cur][0][arow + 16][koff];
    short8 al0 = *(const short8*)&lds[cur][1][arow][koff];
    short8 al1 = *(const short8*)&lds[cur][1][arow + 16][koff];
    short8 bh0 = *(const short8*)&lds[cur][2][brow][koff];
    short8 bh1 = *(const short8*)&lds[cur][2][brow + 16][koff];
    short8 bl0 = *(const short8*)&lds[cur][3][brow][koff];
    short8 bl1 = *(const short8*)&lds[cur][3][brow + 16][koff];
    acc[0][0] = __builtin_amdgcn_mfma_f32_16x16x32_bf16(ah0, bh0, acc[0][0], 0, 0, 0);
    acc[0][1] = __builtin_amdgcn_mfma_f32_16x16x32_bf16(ah0, bh1, acc[0][1], 0, 0, 0);
    acc[1][0] = __builtin_amdgcn_mfma_f32_16x16x32_bf16(ah1, bh0, acc[1][0], 0, 0, 0);
    acc[1][1] = __builtin_amdgcn_mfma_f32_16x16x32_bf16(ah1, bh1, acc[1][1], 0, 0, 0);
    acc[0][0] = __builtin_amdgcn_mfma_f32_16x16x32_bf16(ah0, bl0, acc[0][0], 0, 0, 0);
    acc[0][1] = __builtin_amdgcn_mfma_f32_16x16x32_bf16(ah0, bl1, acc[0][1], 0, 0, 0);
    acc[1][0] = __builtin_amdgcn_mfma_f32_16x16x32_bf16(ah1, bl0, acc[1][0], 0, 0, 0);
    acc[1][1] = __builtin_amdgcn_mfma_f32_16x16x32_bf16(ah1, bl1, acc[1][1], 0, 0, 0);
    acc[0][0] = __builtin_amdgcn_mfma_f32_16x16x32_bf16(al0, bh0, acc[0][0], 0, 0, 0);
    acc[0][1] = __builtin_amdgcn_mfma_f32_16x16x32_bf16(al0, bh1, acc[0][1], 0, 0, 0);
    acc[1][0] = __builtin_amdgcn_mfma_f32_16x16x32_bf16(al1, bh0, acc[1][0], 0, 0, 0);
    acc[1][1] = __builtin_amdgcn_mfma_f32_16x16x32_bf16(al1, bh1, acc[1][1], 0, 0, 0);
    if (s < 7) {
      int nxt = cur ^ 1;
      cvt_store(&lds[nxt][0][r][kq], &lds[nxt][1][r][kq], a0, a1);
      cvt_store(&lds[nxt][2][r][kq], &lds[nxt][3][r][kq], w0, w1);
    }
  }
  const float K2L = 2.8853900817779268f;  // 2*log2(e)
  int b = m0 >> 9;
  int xq = (m0 & 511) + wm * 32 + (lane >> 4) * 4;
#pragma unroll
  for (int mi = 0; mi < 2; mi++) {
#pragma unroll
    for (int ni = 0; ni < 2; ni++) {
      int h = n0 + wn * 32 + ni * 16 + (lane & 15);
      float bb = bias[h];
      f32x4 a = acc[mi][ni];
      float4 o = {fast_exp2(K2L * (a[0] + bb)), fast_exp2(K2L * (a[1] + bb)),
                  fast_exp2(K2L * (a[2] + bb)), fast_exp2(K2L * (a[3] + bb))};
      *(float4*)(ET + ((size_t)b * CH + h) * CNX + xq + mi * 16) = o;
    }
  }
}

// scT[b][r][x] = -2 * sum_h v_w[h] / (exT[b][h][x]*erT[b][h][r] + 1)
// 64(x) x 64(r) tile, grid (8,8,8)=512 blocks, block 512 (two 256-thread
// groups h-splitting the reduction), 4x4 microtile, LDS partial-merge.
__global__ __launch_bounds__(512) void scores_kernel(
    const float* __restrict__ exT, const float* __restrict__ erT,
    const float* __restrict__ v_w, float* __restrict__ scT) {
  // layout: xs0[32*64] rs0[32*64] xs1[32*64] rs1[32*64] vsh[256]
  __shared__ float smem[4 * 2048 + 256];
  int b = blockIdx.z;
  int x0 = blockIdx.x * 64, r0 = blockIdx.y * 64;
  int tid = threadIdx.x;
  int g = tid >> 8;      // reduction group
  int t = tid & 255;
  float* xs = smem + g * 4096;   // [32][64]
  float* rs = xs + 2048;         // [32][64]
  float* vsh = smem + 8192;
  if (tid < 256) vsh[tid] = v_w[tid];
  int tx = t & 15, ty = t >> 4;  // tx -> x(4), ty -> r(4)
  int sr = t >> 4, sc = (t & 15) * 4;  // staging: 16 rows x 16 float4
  int wrot = (tid >> 6) & 7;     // 8 waves -> rotate hq by 0..7
  const float* pX = exT + (size_t)b * CH * CNX + x0 + sc;
  const float* pR = erT + (size_t)b * CH * CNR + r0 + sc;
  int hb = g * 32;
  float4 xa0 = *(const float4*)(pX + (size_t)(hb + sr) * CNX);
  float4 xa1 = *(const float4*)(pX + (size_t)(hb + sr + 16) * CNX);
  float4 ra0 = *(const float4*)(pR + (size_t)(hb + sr) * CNR);
  float4 ra1 = *(const float4*)(pR + (size_t)(hb + sr + 16) * CNR);
  float acc[4][4] = {};
  for (int hc = hb; hc < CH; hc += 64) {
    __syncthreads();
    *(float4*)&xs[sr * 64 + sc] = xa0;
    *(float4*)&xs[(sr + 16) * 64 + sc] = xa1;
    *(float4*)&rs[sr * 64 + sc] = ra0;
    *(float4*)&rs[(sr + 16) * 64 + sc] = ra1;
    __syncthreads();
    if (hc + 64 < CH) {
      xa0 = *(const float4*)(pX + (size_t)(hc + 64 + sr) * CNX);
      xa1 = *(const float4*)(pX + (size_t)(hc + 64 + sr + 16) * CNX);
      ra0 = *(const float4*)(pR + (size_t)(hc + 64 + sr) * CNR);
      ra1 = *(const float4*)(pR + (size_t)(hc + 64 + sr + 16) * CNR);
    }
#pragma unroll 2
    for (int hq = 0; hq < 8; hq++) {
      int h0 = ((hq + wrot) & 7) * 4;
      float4 vv = *(const float4*)&vsh[hc + h0];
      float4 xv0 = *(const float4*)&xs[(h0 + 0) * 64 + tx * 4];
      float4 xv1 = *(const float4*)&xs[(h0 + 1) * 64 + tx * 4];
      float4 xv2 = *(const float4*)&xs[(h0 + 2) * 64 + tx * 4];
      float4 xv3 = *(const float4*)&xs[(h0 + 3) * 64 + tx * 4];
      float4 rv0 = *(const float4*)&rs[(h0 + 0) * 64 + ty * 4];
      float4 rv1 = *(const float4*)&rs[(h0 + 1) * 64 + ty * 4];
      float4 rv2 = *(const float4*)&rs[(h0 + 2) * 64 + ty * 4];
      float4 rv3 = *(const float4*)&rs[(h0 + 3) * 64 + ty * 4];
      float xm0[4] = {xv0.x, xv0.y, xv0.z, xv0.w};
      float xm1[4] = {xv1.x, xv1.y, xv1.z, xv1.w};
      float xm2[4] = {xv2.x, xv2.y, xv2.z, xv2.w};
      float xm3[4] = {xv3.x, xv3.y, xv3.z, xv3.w};
      float rm0[4] = {rv0.x, rv0.y, rv0.z, rv0.w};
      float rm1[4] = {rv1.x, rv1.y, rv1.z, rv1.w};
      float rm2[4] = {rv2.x, rv2.y, rv2.z, rv2.w};
      float rm3[4] = {rv3.x, rv3.y, rv3.z, rv3.w};
#pragma unroll
      for (int i = 0; i < 4; i++)
#pragma unroll
        for (int j = 0; j < 4; j++) {
          float a = fmaf(rm0[i], xm0[j], 1.0f);
          float bb = fmaf(rm1[i], xm1[j], 1.0f);
          float c = fmaf(rm2[i], xm2[j], 1.0f);
          float d = fmaf(rm3[i], xm3[j], 1.0f);
          float q12 = a * bb, q34 = c * d;
          float p12 = fmaf(vv.y, a, vv.x * bb);
          float p34 = fmaf(vv.w, c, vv.z * d);
          float num = fmaf(p34, q12, p12 * q34);
          acc[i][j] = fmaf(num, fast_rcp(q12 * q34), acc[i][j]);
        }
    }
  }
  // merge the two h-partials (reuse smem[0..4096) after barrier)
  __syncthreads();
  float* mg = smem;
  if (g == 1) {
#pragma unroll
    for (int i = 0; i < 4; i++)
#pragma unroll
      for (int j = 0; j < 4; j++)
        mg[t + 256 * (i * 4 + j)] = acc[i][j];
  }
  __syncthreads();
  if (g == 0) {
    float* pO = scT + ((size_t)b * CNR + r0 + ty * 4) * CNX + x0 + tx * 4;
#pragma unroll
    for (int i = 0; i < 4; i++) {
      float4 o = {-2.0f * (acc[i][0] + mg[t + 256 * (i * 4 + 0)]),
                  -2.0f * (acc[i][1] + mg[t + 256 * (i * 4 + 1)]),
                  -2.0f * (acc[i][2] + mg[t + 256 * (i * 4 + 2)]),
                  -2.0f * (acc[i][3] + mg[t + 256 * (i * 4 + 3)])};
      *(float4*)(pO + (size_t)i * CNX) = o;
    }
  }
}

// Fused softmax + weighted sum. Scores bounded so unnormalized exp(s) is
// fp32-safe; numerator and denominator in one K-loop.
// out[b][r][d] = sum_x e(b,r,x)*X[b][x][d] / sum_x e(b,r,x)
// 64(r) x 64(d) tile, grid (8,4,8)=256 blocks, block 512 (two 256-thread
// groups x-splitting the K loop), 4x4 microtile, register prefetch.
__global__ __launch_bounds__(512) void wsum_fused(
    const float* __restrict__ scT, const float* __restrict__ X,
    float* __restrict__ out) {
  // layout: As0[32*68] Bs0[32*68] As1[32*68] Bs1[32*68] dn[128]
  __shared__ float smem[4 * 2176 + 128];
  const float L2E = 1.4426950408889634f;
  int b = blockIdx.z;
  int r0 = blockIdx.x * 64, d0 = blockIdx.y * 64;
  int tid = threadIdx.x;
  int g = tid >> 8;
  int t = tid & 255;
  float* As = smem + g * 4352;   // [32][68] [k][r]
  float* Bs = As + 2176;         // [32][68] [k][d]
  float* dnn = smem + 8704;      // [2][64]
  int tx = t & 15, ty = t >> 4;        // tx -> d(4), ty -> r(4)
  int ar = t >> 2, ak = (t & 3) * 4;   // scT: 64 r-rows, k = ak..ak+3, +16
  int br = t >> 4, bc = (t & 15) * 4;  // X: k-rows br, br+16; d cols bc
  int krot = ((tid >> 6) & 7) * 4;     // 8 waves -> rotate k by 0,4,..,28
  int kb = g * 32;
  const float* pS = scT + ((size_t)b * CNR + r0 + ar) * CNX + ak;
  const float* pB = X + (size_t)b * CNX * CD + d0 + bc;
  float acc[4][4] = {};
  float dsum = 0.0f;
  float4 s0 = *(const float4*)(pS + kb);
  float4 s1 = *(const float4*)(pS + kb + 16);
  float4 b0 = *(const float4*)(pB + (size_t)(kb + br) * CD);
  float4 b1 = *(const float4*)(pB + (size_t)(kb + br + 16) * CD);
  for (int kt = kb; kt < CNX; kt += 64) {
    float4 e0 = {fast_exp2(s0.x * L2E), fast_exp2(s0.y * L2E),
                 fast_exp2(s0.z * L2E), fast_exp2(s0.w * L2E)};
    float4 e1 = {fast_exp2(s1.x * L2E), fast_exp2(s1.y * L2E),
                 fast_exp2(s1.z * L2E), fast_exp2(s1.w * L2E)};
    dsum += ((e0.x + e0.y) + (e0.z + e0.w)) + ((e1.x + e1.y) + (e1.z + e1.w));
    __syncthreads();
    As[(ak + 0) * 68 + ar] = e0.x;
    As[(ak + 1) * 68 + ar] = e0.y;
    As[(ak + 2) * 68 + ar] = e0.z;
    As[(ak + 3) * 68 + ar] = e0.w;
    As[(ak + 16) * 68 + ar] = e1.x;
    As[(ak + 17) * 68 + ar] = e1.y;
    As[(ak + 18) * 68 + ar] = e1.z;
    As[(ak + 19) * 68 + ar] = e1.w;
    *(float4*)&Bs[br * 68 + bc] = b0;
    *(float4*)&Bs[(br + 16) * 68 + bc] = b1;
    __syncthreads();
    if (kt + 64 < CNX) {
      s0 = *(const float4*)(pS + kt + 64);
      s1 = *(const float4*)(pS + kt + 80);
      b0 = *(const float4*)(pB + (size_t)(kt + 64 + br) * CD);
      b1 = *(const float4*)(pB + (size_t)(kt + 64 + br + 16) * CD);
    }
#pragma unroll 8
    for (int k = 0; k < 32; k++) {
      int kk = (k + krot) & 31;
      float4 a4 = *(const float4*)&As[kk * 68 + ty * 4];
      float4 b4 = *(const float4*)&Bs[kk * 68 + tx * 4];
      float am[4] = {a4.x, a4.y, a4.z, a4.w};
      float bm[4] = {b4.x, b4.y, b4.z, b4.w};
#pragma unroll
      for (int i = 0; i < 4; i++)
#pragma unroll
        for (int j = 0; j < 4; j++)
          acc[i][j] = fmaf(am[i], bm[j], acc[i][j]);
    }
  }
  // denominator partial: 4 lanes (t&3) share row ar
  dsum += __shfl_xor(dsum, 1, 64);
  dsum += __shfl_xor(dsum, 2, 64);
  if ((t & 3) == 0) dnn[g * 64 + ar] = dsum;
  __syncthreads();
  // merge the two x-partials (reuse smem[0..4096) after barrier; dn is safe)
  float* mg = smem;
  if (g == 1) {
#pragma unroll
    for (int i = 0; i < 4; i++)
#pragma unroll
      for (int j = 0; j < 4; j++)
        mg[t + 256 * (i * 4 + j)] = acc[i][j];
  }
  __syncthreads();
  if (g == 0) {
    float invm[4];
#pragma unroll
    for (int i = 0; i < 4; i++)
      invm[i] = fast_rcp(dnn[ty * 4 + i] + dnn[64 + ty * 4 + i]);
    float* pO = out + ((size_t)b * CNR + r0 + ty * 4) * CD + d0 + tx * 4;
#pragma unroll
    for (int i = 0; i < 4; i++) {
      float4 o = {
          (acc[i][0] + mg[t + 256 * (i * 4 + 0)]) * invm[i],
          (acc[i][1] + mg[t + 256 * (i * 4 + 1)]) * invm[i],
          (acc[i][2] + mg[t + 256 * (i * 4 + 2)]) * invm[i],
          (acc[i][3] + mg[t + 256 * (i * 4 + 3)]) * invm[i]};
      *(float4*)(pO + (size_t)i * CD) = o;
    }
  }
}

extern "C" void kernel_launch(void* const* d_in, const int* in_sizes, int n_in,
                              void* d_out, int out_size, void* d_ws, size_t ws_size,
                              hipStream_t stream) {
  const float* X     = (const float*)d_in[0];
  const float* ref   = (const float*)d_in[1];
  const float* W_X   = (const float*)d_in[2];
  const float* b_X   = (const float*)d_in[3];
  const float* W_ref = (const float*)d_in[4];
  const float* b_ref = (const float*)d_in[5];
  const float* v_w   = (const float*)d_in[6];
  float* out = (float*)d_out;
  float* ws  = (float*)d_ws;

  float* exT = ws;                       // [B][H][NX] = 1,048,576 floats
  float* erT = ws + 1048576;             // [B][H][NR] = 1,048,576 floats
  float* scT = ws + 2097152;             // [B][NR][NX] = 2,097,152 floats

  proj_mfma<<<dim3(64, 4, 2), 256, 0, stream>>>(X, ref, W_X, W_ref, b_X, b_ref, exT, erT);
  scores_kernel<<<dim3(8, 8, 8), 512, 0, stream>>>(exT, erT, v_w, scT);
  wsum_fused<<<dim3(8, 4, 8), 512, 0, stream>>>(scT, X, out);
}

// Round 6
// 132.836 us; speedup vs baseline: 11.6702x; 1.1011x over previous
//
#include <hip/hip_runtime.h>
#include <math.h>

#define CB 8
#define CNX 512
#define CNR 512
#define CD 256
#define CH 256

typedef __attribute__((ext_vector_type(8))) short short8;
typedef __attribute__((ext_vector_type(4))) float f32x4;

__device__ __forceinline__ float fast_rcp(float x) {
#if __has_builtin(__builtin_amdgcn_rcpf)
  return __builtin_amdgcn_rcpf(x);
#else
  return 1.0f / x;
#endif
}
__device__ __forceinline__ float fast_exp2(float x) {
#if __has_builtin(__builtin_amdgcn_exp2f)
  return __builtin_amdgcn_exp2f(x);
#else
  return exp2f(x);
#endif
}

// Split a float into bf16 hi (truncation) + bf16 lo (residual, truncated),
// packing 8 consecutive k-values into uint4 hi and uint4 lo, store to LDS.
__device__ __forceinline__ void cvt_store(unsigned short* dstH,
                                          unsigned short* dstL,
                                          float4 v0, float4 v1) {
  unsigned u0x = __float_as_uint(v0.x), u0y = __float_as_uint(v0.y);
  unsigned u0z = __float_as_uint(v0.z), u0w = __float_as_uint(v0.w);
  unsigned u1x = __float_as_uint(v1.x), u1y = __float_as_uint(v1.y);
  unsigned u1z = __float_as_uint(v1.z), u1w = __float_as_uint(v1.w);
  uint4 H;
  H.x = (u0x >> 16) | (u0y & 0xFFFF0000u);
  H.y = (u0z >> 16) | (u0w & 0xFFFF0000u);
  H.z = (u1x >> 16) | (u1y & 0xFFFF0000u);
  H.w = (u1z >> 16) | (u1w & 0xFFFF0000u);
  float r0x = v0.x - __uint_as_float(u0x & 0xFFFF0000u);
  float r0y = v0.y - __uint_as_float(u0y & 0xFFFF0000u);
  float r0z = v0.z - __uint_as_float(u0z & 0xFFFF0000u);
  float r0w = v0.w - __uint_as_float(u0w & 0xFFFF0000u);
  float r1x = v1.x - __uint_as_float(u1x & 0xFFFF0000u);
  float r1y = v1.y - __uint_as_float(u1y & 0xFFFF0000u);
  float r1z = v1.z - __uint_as_float(u1z & 0xFFFF0000u);
  float r1w = v1.w - __uint_as_float(u1w & 0xFFFF0000u);
  uint4 L;
  L.x = (__float_as_uint(r0x) >> 16) | (__float_as_uint(r0y) & 0xFFFF0000u);
  L.y = (__float_as_uint(r0z) >> 16) | (__float_as_uint(r0w) & 0xFFFF0000u);
  L.z = (__float_as_uint(r1x) >> 16) | (__float_as_uint(r1y) & 0xFFFF0000u);
  L.w = (__float_as_uint(r1z) >> 16) | (__float_as_uint(r1w) & 0xFFFF0000u);
  *(uint4*)dstH = H;
  *(uint4*)dstL = L;
}

// Split float4 -> bf16 hi ushort4 + lo ushort4 (truncation + residual).
__device__ __forceinline__ void split4(float4 v, ushort4* H, ushort4* L) {
  unsigned ux = __float_as_uint(v.x), uy = __float_as_uint(v.y);
  unsigned uz = __float_as_uint(v.z), uw = __float_as_uint(v.w);
  H->x = (unsigned short)(ux >> 16);
  H->y = (unsigned short)(uy >> 16);
  H->z = (unsigned short)(uz >> 16);
  H->w = (unsigned short)(uw >> 16);
  float rx = v.x - __uint_as_float(ux & 0xFFFF0000u);
  float ry = v.y - __uint_as_float(uy & 0xFFFF0000u);
  float rz = v.z - __uint_as_float(uz & 0xFFFF0000u);
  float rw = v.w - __uint_as_float(uw & 0xFFFF0000u);
  L->x = (unsigned short)(__float_as_uint(rx) >> 16);
  L->y = (unsigned short)(__float_as_uint(ry) >> 16);
  L->z = (unsigned short)(__float_as_uint(rz) >> 16);
  L->w = (unsigned short)(__float_as_uint(rw) >> 16);
}

// Fused projections via split-bf16 MFMA (3 mfma: hi*hi + hi*lo + lo*hi).
// ET[b][h][x] = exp2(K2L*(sum_k A[m][k]*W[h][k] + bias[h])), m=b*512+x
// 64(m) x 64(h) tile, K-step 32, grid (64,4,2), block 256 = 4 waves,
// each wave a 32x32 quadrant (2x2 MFMA 16x16x32 frags). Double-buffered
// LDS (1 barrier/step), rows padded to 40 ushort (2-way bank alias, free).
__global__ __launch_bounds__(256) void proj_mfma(
    const float* __restrict__ A0, const float* __restrict__ A1,
    const float* __restrict__ W0, const float* __restrict__ W1,
    const float* __restrict__ bias0, const float* __restrict__ bias1,
    float* __restrict__ E0, float* __restrict__ E1) {
  // [buf][mat: Ah,Al,Wh,Wl][row][k] ; row stride 40 ushort = 80 B (16B mult)
  __shared__ unsigned short lds[2][4][64][40];
  const int K = CD;
  int z = blockIdx.z;
  const float* A = z ? A1 : A0;
  const float* W = z ? W1 : W0;
  const float* bias = z ? bias1 : bias0;
  float* ET = z ? E1 : E0;
  int m0 = blockIdx.x * 64, n0 = blockIdx.y * 64;
  int tid = threadIdx.x;
  int lane = tid & 63, w = tid >> 6;
  int wm = w >> 1, wn = w & 1;  // wave quadrant: m-half, n-half
  // staging: 64 rows x (4 threads/row x 8 k)
  int r = tid >> 2, kq = (tid & 3) * 8;
  const float* pA = A + (size_t)(m0 + r) * K + kq;
  const float* pW = W + (size_t)(n0 + r) * K + kq;
  f32x4 acc[2][2] = {};
  float4 a0 = *(const float4*)(pA);
  float4 a1 = *(const float4*)(pA + 4);
  float4 w0 = *(const float4*)(pW);
  float4 w1 = *(const float4*)(pW + 4);
  cvt_store(&lds[0][0][r][kq], &lds[0][1][r][kq], a0, a1);
  cvt_store(&lds[0][2][r][kq], &lds[0][3][r][kq], w0, w1);
  for (int s = 0; s < 8; s++) {
    __syncthreads();
    if (s < 7) {
      int kt = (s + 1) * 32;
      a0 = *(const float4*)(pA + kt);
      a1 = *(const float4*)(pA + kt + 4);
      w0 = *(const float4*)(pW + kt);
      w1 = *(const float4*)(pW + kt + 4);
    }
    int cur = s & 1;
    int arow = wm * 32 + (lane & 15);
    int brow = wn * 32 + (lane & 15);
    int koff = (lane >> 4) * 8;
    short8 ah0 = *(const short8*)&lds[cur][0][arow][koff];
    short8 ah1 = *(const short8*)&lds[cur][0][arow + 16][koff];
    short8 al0 = *(const short8*)&lds[cur][1][arow][koff];
    short8 al1 = *(const short8*)&lds[cur][1][arow + 16][koff];
    short8 bh0 = *(const short8*)&lds[cur][2][brow][koff];
    short8 bh1 = *(const short8*)&lds[cur][2][brow + 16][koff];
    short8 bl0 = *(const short8*)&lds[cur][3][brow][koff];
    short8 bl1 = *(const short8*)&lds[cur][3][brow + 16][koff];
    acc[0][0] = __builtin_amdgcn_mfma_f32_16x16x32_bf16(ah0, bh0, acc[0][0], 0, 0, 0);
    acc[0][1] = __builtin_amdgcn_mfma_f32_16x16x32_bf16(ah0, bh1, acc[0][1], 0, 0, 0);
    acc[1][0] = __builtin_amdgcn_mfma_f32_16x16x32_bf16(ah1, bh0, acc[1][0], 0, 0, 0);
    acc[1][1] = __builtin_amdgcn_mfma_f32_16x16x32_bf16(ah1, bh1, acc[1][1], 0, 0, 0);
    acc[0][0] = __builtin_amdgcn_mfma_f32_16x16x32_bf16(ah0, bl0, acc[0][0], 0, 0, 0);
    acc[0][1] = __builtin_amdgcn_mfma_f32_16x16x32_bf16(ah0, bl1, acc[0][1], 0, 0, 0);
    acc[1][0] = __builtin_amdgcn_mfma_f32_16x16x32_bf16(ah1, bl0, acc[1][0], 0, 0, 0);
    acc[1][1] = __builtin_amdgcn_mfma_f32_16x16x32_bf16(ah1, bl1, acc[1][1], 0, 0, 0);
    acc[0][0] = __builtin_amdgcn_mfma_f32_16x16x32_bf16(al0, bh0, acc[0][0], 0, 0, 0);
    acc[0][1] = __builtin_amdgcn_mfma_f32_16x16x32_bf16(al0, bh1, acc[0][1], 0, 0, 0);
    acc[1][0] = __builtin_amdgcn_mfma_f32_16x16x32_bf16(al1, bh0, acc[1][0], 0, 0, 0);
    acc[1][1] = __builtin_amdgcn_mfma_f32_16x16x32_bf16(al1, bh1, acc[1][1], 0, 0, 0);
    if (s < 7) {
      int nxt = cur ^ 1;
      cvt_store(&lds[nxt][0][r][kq], &lds[nxt][1][r][kq], a0, a1);
      cvt_store(&lds[nxt][2][r][kq], &lds[nxt][3][r][kq], w0, w1);
    }
  }
  const float K2L = 2.8853900817779268f;  // 2*log2(e)
  int b = m0 >> 9;
  int xq = (m0 & 511) + wm * 32 + (lane >> 4) * 4;
#pragma unroll
  for (int mi = 0; mi < 2; mi++) {
#pragma unroll
    for (int ni = 0; ni < 2; ni++) {
      int h = n0 + wn * 32 + ni * 16 + (lane & 15);
      float bb = bias[h];
      f32x4 a = acc[mi][ni];
      float4 o = {fast_exp2(K2L * (a[0] + bb)), fast_exp2(K2L * (a[1] + bb)),
                  fast_exp2(K2L * (a[2] + bb)), fast_exp2(K2L * (a[3] + bb))};
      *(float4*)(ET + ((size_t)b * CH + h) * CNX + xq + mi * 16) = o;
    }
  }
}

// scT[b][r][x] = -2 * sum_h v_w[h] / (exT[b][h][x]*erT[b][h][r] + 1)
// 64(x) x 64(r) tile, grid (8,8,8)=512 blocks, block 512 (two 256-thread
// groups h-splitting the reduction), 4x4 microtile, LDS partial-merge.
__global__ __launch_bounds__(512) void scores_kernel(
    const float* __restrict__ exT, const float* __restrict__ erT,
    const float* __restrict__ v_w, float* __restrict__ scT) {
  // layout: xs0[32*64] rs0[32*64] xs1[32*64] rs1[32*64] vsh[256]
  __shared__ float smem[4 * 2048 + 256];
  int b = blockIdx.z;
  int x0 = blockIdx.x * 64, r0 = blockIdx.y * 64;
  int tid = threadIdx.x;
  int g = tid >> 8;      // reduction group
  int t = tid & 255;
  float* xs = smem + g * 4096;   // [32][64]
  float* rs = xs + 2048;         // [32][64]
  float* vsh = smem + 8192;
  if (tid < 256) vsh[tid] = v_w[tid];
  int tx = t & 15, ty = t >> 4;  // tx -> x(4), ty -> r(4)
  int sr = t >> 4, sc = (t & 15) * 4;  // staging: 16 rows x 16 float4
  int wrot = (tid >> 6) & 7;     // 8 waves -> rotate hq by 0..7
  const float* pX = exT + (size_t)b * CH * CNX + x0 + sc;
  const float* pR = erT + (size_t)b * CH * CNR + r0 + sc;
  int hb = g * 32;
  float4 xa0 = *(const float4*)(pX + (size_t)(hb + sr) * CNX);
  float4 xa1 = *(const float4*)(pX + (size_t)(hb + sr + 16) * CNX);
  float4 ra0 = *(const float4*)(pR + (size_t)(hb + sr) * CNR);
  float4 ra1 = *(const float4*)(pR + (size_t)(hb + sr + 16) * CNR);
  float acc[4][4] = {};
  for (int hc = hb; hc < CH; hc += 64) {
    __syncthreads();
    *(float4*)&xs[sr * 64 + sc] = xa0;
    *(float4*)&xs[(sr + 16) * 64 + sc] = xa1;
    *(float4*)&rs[sr * 64 + sc] = ra0;
    *(float4*)&rs[(sr + 16) * 64 + sc] = ra1;
    __syncthreads();
    if (hc + 64 < CH) {
      xa0 = *(const float4*)(pX + (size_t)(hc + 64 + sr) * CNX);
      xa1 = *(const float4*)(pX + (size_t)(hc + 64 + sr + 16) * CNX);
      ra0 = *(const float4*)(pR + (size_t)(hc + 64 + sr) * CNR);
      ra1 = *(const float4*)(pR + (size_t)(hc + 64 + sr + 16) * CNR);
    }
#pragma unroll 2
    for (int hq = 0; hq < 8; hq++) {
      int h0 = ((hq + wrot) & 7) * 4;
      float4 vv = *(const float4*)&vsh[hc + h0];
      float4 xv0 = *(const float4*)&xs[(h0 + 0) * 64 + tx * 4];
      float4 xv1 = *(const float4*)&xs[(h0 + 1) * 64 + tx * 4];
      float4 xv2 = *(const float4*)&xs[(h0 + 2) * 64 + tx * 4];
      float4 xv3 = *(const float4*)&xs[(h0 + 3) * 64 + tx * 4];
      float4 rv0 = *(const float4*)&rs[(h0 + 0) * 64 + ty * 4];
      float4 rv1 = *(const float4*)&rs[(h0 + 1) * 64 + ty * 4];
      float4 rv2 = *(const float4*)&rs[(h0 + 2) * 64 + ty * 4];
      float4 rv3 = *(const float4*)&rs[(h0 + 3) * 64 + ty * 4];
      float xm0[4] = {xv0.x, xv0.y, xv0.z, xv0.w};
      float xm1[4] = {xv1.x, xv1.y, xv1.z, xv1.w};
      float xm2[4] = {xv2.x, xv2.y, xv2.z, xv2.w};
      float xm3[4] = {xv3.x, xv3.y, xv3.z, xv3.w};
      float rm0[4] = {rv0.x, rv0.y, rv0.z, rv0.w};
      float rm1[4] = {rv1.x, rv1.y, rv1.z, rv1.w};
      float rm2[4] = {rv2.x, rv2.y, rv2.z, rv2.w};
      float rm3[4] = {rv3.x, rv3.y, rv3.z, rv3.w};
#pragma unroll
      for (int i = 0; i < 4; i++)
#pragma unroll
        for (int j = 0; j < 4; j++) {
          float a = fmaf(rm0[i], xm0[j], 1.0f);
          float bb = fmaf(rm1[i], xm1[j], 1.0f);
          float c = fmaf(rm2[i], xm2[j], 1.0f);
          float d = fmaf(rm3[i], xm3[j], 1.0f);
          float q12 = a * bb, q34 = c * d;
          float p12 = fmaf(vv.y, a, vv.x * bb);
          float p34 = fmaf(vv.w, c, vv.z * d);
          float num = fmaf(p34, q12, p12 * q34);
          acc[i][j] = fmaf(num, fast_rcp(q12 * q34), acc[i][j]);
        }
    }
  }
  // merge the two h-partials (reuse smem[0..4096) after barrier)
  __syncthreads();
  float* mg = smem;
  if (g == 1) {
#pragma unroll
    for (int i = 0; i < 4; i++)
#pragma unroll
      for (int j = 0; j < 4; j++)
        mg[t + 256 * (i * 4 + j)] = acc[i][j];
  }
  __syncthreads();
  if (g == 0) {
    float* pO = scT + ((size_t)b * CNR + r0 + ty * 4) * CNX + x0 + tx * 4;
#pragma unroll
    for (int i = 0; i < 4; i++) {
      float4 o = {-2.0f * (acc[i][0] + mg[t + 256 * (i * 4 + 0)]),
                  -2.0f * (acc[i][1] + mg[t + 256 * (i * 4 + 1)]),
                  -2.0f * (acc[i][2] + mg[t + 256 * (i * 4 + 2)]),
                  -2.0f * (acc[i][3] + mg[t + 256 * (i * 4 + 3)])};
      *(float4*)(pO + (size_t)i * CNX) = o;
    }
  }
}

// Fused softmax + weighted sum via split-bf16 MFMA.
// out[b][r][d] = sum_x P[r][x]*X[x][d] / sum_x P[r][x], P = exp(scT).
// 64(r) x 64(d) tile, K-step 32(x), grid (8,4,8)=256 blocks, block 512 =
// 8 waves (2 r-halves x 4 d-quarters), 3 mfma per frag-pair (hi*hi +
// hi*lo + lo*hi). LDS rows = [hi(32k) | lo(32k)] bf16 = 128 B with T2
// XOR swizzle (slot ^= row&7) -> conflict-free b128 frag reads.
// X transposed in-register at staging (coalesced loads along d).
__global__ __launch_bounds__(512) void wsum_mfma(
    const float* __restrict__ scT, const float* __restrict__ X,
    float* __restrict__ out) {
  // [buf][mat: P, Xt][row][64 ushort]; row = [hi 32k | lo 32k], 8 slots x 16B
  __shared__ unsigned short lds[2][2][64][64];
  __shared__ float dn[64];
  const float L2E = 1.4426950408889634f;
  int b = blockIdx.z;
  int r0 = blockIdx.x * 64, d0 = blockIdx.y * 64;
  int tid = threadIdx.x;
  int lane = tid & 63, w = tid >> 6;
  int wm = w >> 2, wn = w & 3;  // r-half (32), d-quarter (16)
  // P staging: row pr (64), 4 k per thread
  int pr = tid >> 3, pxk = (tid & 7) * 4;
  int psl = pxk >> 3, pof = pxk & 7;  // slot 0..3, offset 0 or 4
  // X staging: d-row xd (64), 4 x per thread (in-register transpose)
  int xd = tid & 63, xx = (tid >> 6) * 4;
  int xsl = xx >> 3, xof = xx & 7;
  const float* pS = scT + ((size_t)b * CNR + r0 + pr) * CNX + pxk;
  const float* pX = X + ((size_t)b * CNX + xx) * CD + d0 + xd;
  f32x4 acc0 = {}, acc1 = {};
  float dsum = 0.0f;
  float4 sv = *(const float4*)(pS);
  float4 xv = {pX[0], pX[CD], pX[2 * CD], pX[3 * CD]};
  {
    float4 ev = {fast_exp2(sv.x * L2E), fast_exp2(sv.y * L2E),
                 fast_exp2(sv.z * L2E), fast_exp2(sv.w * L2E)};
    dsum += (ev.x + ev.y) + (ev.z + ev.w);
    ushort4 H, L;
    split4(ev, &H, &L);
    unsigned short* rp = &lds[0][0][pr][0];
    *(ushort4*)(rp + ((psl ^ (pr & 7)) << 3) + pof) = H;
    *(ushort4*)(rp + (((psl + 4) ^ (pr & 7)) << 3) + pof) = L;
    split4(xv, &H, &L);
    unsigned short* rx = &lds[0][1][xd][0];
    *(ushort4*)(rx + ((xsl ^ (xd & 7)) << 3) + xof) = H;
    *(ushort4*)(rx + (((xsl + 4) ^ (xd & 7)) << 3) + xof) = L;
  }
  int q = lane >> 4;            // k-slot 0..3
  int mr0 = wm * 32 + (lane & 15);
  int mr1 = mr0 + 16;
  int nr = wn * 16 + (lane & 15);
  for (int s = 0; s < 16; s++) {
    __syncthreads();
    if (s < 15) {
      int kt = (s + 1) * 32;
      sv = *(const float4*)(pS + kt);
      xv.x = pX[(size_t)(kt + 0) * CD];
      xv.y = pX[(size_t)(kt + 1) * CD];
      xv.z = pX[(size_t)(kt + 2) * CD];
      xv.w = pX[(size_t)(kt + 3) * CD];
    }
    int cur = s & 1;
    const unsigned short* Pt = &lds[cur][0][0][0];
    const unsigned short* Xt = &lds[cur][1][0][0];
    short8 ah0 = *(const short8*)(Pt + mr0 * 64 + ((q ^ (mr0 & 7)) << 3));
    short8 al0 = *(const short8*)(Pt + mr0 * 64 + (((q + 4) ^ (mr0 & 7)) << 3));
    short8 ah1 = *(const short8*)(Pt + mr1 * 64 + ((q ^ (mr1 & 7)) << 3));
    short8 al1 = *(const short8*)(Pt + mr1 * 64 + (((q + 4) ^ (mr1 & 7)) << 3));
    short8 bh = *(const short8*)(Xt + nr * 64 + ((q ^ (nr & 7)) << 3));
    short8 bl = *(const short8*)(Xt + nr * 64 + (((q + 4) ^ (nr & 7)) << 3));
    acc0 = __builtin_amdgcn_mfma_f32_16x16x32_bf16(ah0, bh, acc0, 0, 0, 0);
    acc1 = __builtin_amdgcn_mfma_f32_16x16x32_bf16(ah1, bh, acc1, 0, 0, 0);
    acc0 = __builtin_amdgcn_mfma_f32_16x16x32_bf16(ah0, bl, acc0, 0, 0, 0);
    acc1 = __builtin_amdgcn_mfma_f32_16x16x32_bf16(ah1, bl, acc1, 0, 0, 0);
    acc0 = __builtin_amdgcn_mfma_f32_16x16x32_bf16(al0, bh, acc0, 0, 0, 0);
    acc1 = __builtin_amdgcn_mfma_f32_16x16x32_bf16(al1, bh, acc1, 0, 0, 0);
    if (s < 15) {
      int nxt = cur ^ 1;
      float4 ev = {fast_exp2(sv.x * L2E), fast_exp2(sv.y * L2E),
                   fast_exp2(sv.z * L2E), fast_exp2(sv.w * L2E)};
      dsum += (ev.x + ev.y) + (ev.z + ev.w);
      ushort4 H, L;
      split4(ev, &H, &L);
      unsigned short* rp = &lds[nxt][0][pr][0];
      *(ushort4*)(rp + ((psl ^ (pr & 7)) << 3) + pof) = H;
      *(ushort4*)(rp + (((psl + 4) ^ (pr & 7)) << 3) + pof) = L;
      split4(xv, &H, &L);
      unsigned short* rx = &lds[nxt][1][xd][0];
      *(ushort4*)(rx + ((xsl ^ (xd & 7)) << 3) + xof) = H;
      *(ushort4*)(rx + (((xsl + 4) ^ (xd & 7)) << 3) + xof) = L;
    }
  }
  // denominator: 8 threads (tid&7) share row pr
  dsum += __shfl_xor(dsum, 1, 64);
  dsum += __shfl_xor(dsum, 2, 64);
  dsum += __shfl_xor(dsum, 4, 64);
  if ((tid & 7) == 0) dn[pr] = dsum;
  __syncthreads();
  int col = d0 + wn * 16 + (lane & 15);
  float* pO = out + ((size_t)b * CNR + r0) * CD + col;
#pragma unroll
  for (int j = 0; j < 4; j++) {
    int row = wm * 32 + q * 4 + j;
    pO[(size_t)row * CD] = acc0[j] * fast_rcp(dn[row]);
  }
#pragma unroll
  for (int j = 0; j < 4; j++) {
    int row = wm * 32 + 16 + q * 4 + j;
    pO[(size_t)row * CD] = acc1[j] * fast_rcp(dn[row]);
  }
}

extern "C" void kernel_launch(void* const* d_in, const int* in_sizes, int n_in,
                              void* d_out, int out_size, void* d_ws, size_t ws_size,
                              hipStream_t stream) {
  const float* X     = (const float*)d_in[0];
  const float* ref   = (const float*)d_in[1];
  const float* W_X   = (const float*)d_in[2];
  const float* b_X   = (const float*)d_in[3];
  const float* W_ref = (const float*)d_in[4];
  const float* b_ref = (const float*)d_in[5];
  const float* v_w   = (const float*)d_in[6];
  float* out = (float*)d_out;
  float* ws  = (float*)d_ws;

  float* exT = ws;                       // [B][H][NX] = 1,048,576 floats
  float* erT = ws + 1048576;             // [B][H][NR] = 1,048,576 floats
  float* scT = ws + 2097152;             // [B][NR][NX] = 2,097,152 floats

  proj_mfma<<<dim3(64, 4, 2), 256, 0, stream>>>(X, ref, W_X, W_ref, b_X, b_ref, exT, erT);
  scores_kernel<<<dim3(8, 8, 8), 512, 0, stream>>>(exT, erT, v_w, scT);
  wsum_mfma<<<dim3(8, 4, 8), 512, 0, stream>>>(scT, X, out);
}